// Round 1
// baseline (1808.026 us; speedup 1.0000x reference)
//
#include <hip/hip_runtime.h>

#define NB 2
#define CDIM 512
#define SEQ 4096
#define HID 512
#define NHEADS 8
#define HDIM 64
#define ATT_SCALE 0.125f

// ---------------------------------------------------------------------------
// Tiled fp32 GEMM: out[m][n] = sum_k A[m][k] * W[k][n] (+bias) (+gelu)
// ATRANS: A stored [K][M] (row stride M) -- used for x/context which are [C][S].
// Block: 256 threads = 16x16, each computes a 4x4 microtile of a 64x64 tile.
// ---------------------------------------------------------------------------
template <bool ATRANS, bool DO_GELU, bool HAS_BIAS>
__global__ __launch_bounds__(256) void gemm_f32(
    const float* __restrict__ A, const float* __restrict__ W,
    const float* __restrict__ bias, float* __restrict__ out,
    const int M, const int N, const int K,
    const long aStride, const long oStride) {
  __shared__ __align__(16) float As[16][68];  // As[k][m]
  __shared__ __align__(16) float Bs[16][68];  // Bs[k][n]
  const int t = threadIdx.x;
  const int tx = t & 15, ty = t >> 4;
  const int m0 = blockIdx.y * 64, n0 = blockIdx.x * 64;
  const float* Ab = A + (long)blockIdx.z * aStride;
  float* Ob = out + (long)blockIdx.z * oStride;
  float acc[4][4] = {};

  for (int k0 = 0; k0 < K; k0 += 16) {
    if (ATRANS) {
      // A[k][m] row stride M: load 16x64 directly (coalesced along m)
      const int r = t >> 4, c = (t & 15) * 4;
      const float4 a4 = *(const float4*)(Ab + (long)(k0 + r) * M + (m0 + c));
      *(float4*)&As[r][c] = a4;
    } else {
      // A[m][k] row stride K: load 64x16, store transposed into As[k][m]
      const int r = t >> 2, c = (t & 3) * 4;
      const float4 a4 = *(const float4*)(Ab + (long)(m0 + r) * K + (k0 + c));
      As[c + 0][r] = a4.x;
      As[c + 1][r] = a4.y;
      As[c + 2][r] = a4.z;
      As[c + 3][r] = a4.w;
    }
    {
      // W[k][n] row stride N: load 16x64 directly
      const int r = t >> 4, c = (t & 15) * 4;
      const float4 b4 = *(const float4*)(W + (long)(k0 + r) * N + (n0 + c));
      *(float4*)&Bs[r][c] = b4;
    }
    __syncthreads();
#pragma unroll
    for (int k = 0; k < 16; ++k) {
      const float4 a4 = *(const float4*)&As[k][ty * 4];
      const float4 b4 = *(const float4*)&Bs[k][tx * 4];
      const float av[4] = {a4.x, a4.y, a4.z, a4.w};
      const float bv[4] = {b4.x, b4.y, b4.z, b4.w};
#pragma unroll
      for (int i = 0; i < 4; ++i)
#pragma unroll
        for (int j = 0; j < 4; ++j)
          acc[i][j] = fmaf(av[i], bv[j], acc[i][j]);
    }
    __syncthreads();
  }

#pragma unroll
  for (int i = 0; i < 4; ++i) {
    const int m = m0 + ty * 4 + i;
    float vv[4];
#pragma unroll
    for (int j = 0; j < 4; ++j) {
      float v = acc[i][j];
      if (HAS_BIAS) v += bias[n0 + tx * 4 + j];
      if (DO_GELU) v = 0.5f * v * (1.0f + erff(v * 0.7071067811865476f));
      vv[j] = v;
    }
    float4 r4;
    r4.x = vv[0]; r4.y = vv[1]; r4.z = vv[2]; r4.w = vv[3];
    *(float4*)(Ob + (long)m * N + (n0 + tx * 4)) = r4;
  }
}

// ---------------------------------------------------------------------------
// Flash attention, fp32, one (b, head, 64-row q-tile) per block.
// Q,K transposed in LDS (Qt[d][row]); V direct (Vs[row][d]). Scores stay in
// registers; row softmax via shfl_xor over the 16 tx lanes; P redistributed
// to PV consumers via lane shuffles (no LDS round-trip for S).
// ---------------------------------------------------------------------------
__global__ __launch_bounds__(256) void attn_f32(
    const float* __restrict__ qp, const float* __restrict__ kp,
    const float* __restrict__ vp, float* __restrict__ op) {
  __shared__ __align__(16) float Qt[HDIM][68];
  __shared__ __align__(16) float Kt[HDIM][68];
  __shared__ __align__(16) float Vs[64][68];
  const int t = threadIdx.x;
  const int tx = t & 15, ty = t >> 4;
  const int lane = t & 63;
  const int q0 = blockIdx.x * 64;
  const long base = (long)blockIdx.z * SEQ * HID + (long)blockIdx.y * HDIM;

  // load Q tile transposed
  for (int idx = t; idx < 64 * 16; idx += 256) {
    const int r = idx >> 4, c = (idx & 15) * 4;
    const float4 a4 = *(const float4*)(qp + base + (long)(q0 + r) * HID + c);
    Qt[c + 0][r] = a4.x;
    Qt[c + 1][r] = a4.y;
    Qt[c + 2][r] = a4.z;
    Qt[c + 3][r] = a4.w;
  }
  float m[4], l[4], acc[4][4] = {};
#pragma unroll
  for (int i = 0; i < 4; ++i) {
    m[i] = -1e30f;
    l[i] = 0.0f;
  }
  __syncthreads();

  for (int j0 = 0; j0 < SEQ; j0 += 64) {
    // load K (transposed) and V (direct) tiles
    for (int idx = t; idx < 64 * 16; idx += 256) {
      const int r = idx >> 4, c = (idx & 15) * 4;
      const float4 k4 = *(const float4*)(kp + base + (long)(j0 + r) * HID + c);
      Kt[c + 0][r] = k4.x;
      Kt[c + 1][r] = k4.y;
      Kt[c + 2][r] = k4.z;
      Kt[c + 3][r] = k4.w;
      const float4 v4 = *(const float4*)(vp + base + (long)(j0 + r) * HID + c);
      *(float4*)&Vs[r][c] = v4;
    }
    __syncthreads();

    // S tile = Q K^T (rows ty*4+i, cols tx*4+j)
    float p[4][4] = {};
#pragma unroll
    for (int d = 0; d < HDIM; ++d) {
      const float4 a4 = *(const float4*)&Qt[d][ty * 4];
      const float4 b4 = *(const float4*)&Kt[d][tx * 4];
      const float av[4] = {a4.x, a4.y, a4.z, a4.w};
      const float bv[4] = {b4.x, b4.y, b4.z, b4.w};
#pragma unroll
      for (int i = 0; i < 4; ++i)
#pragma unroll
        for (int j = 0; j < 4; ++j)
          p[i][j] = fmaf(av[i], bv[j], p[i][j]);
    }

    // online softmax per row (row spread across 16 tx lanes, 4 cols each)
#pragma unroll
    for (int i = 0; i < 4; ++i) {
#pragma unroll
      for (int j = 0; j < 4; ++j) p[i][j] *= ATT_SCALE;
      float mt = fmaxf(fmaxf(p[i][0], p[i][1]), fmaxf(p[i][2], p[i][3]));
      mt = fmaxf(mt, __shfl_xor(mt, 1));
      mt = fmaxf(mt, __shfl_xor(mt, 2));
      mt = fmaxf(mt, __shfl_xor(mt, 4));
      mt = fmaxf(mt, __shfl_xor(mt, 8));
      const float mnew = fmaxf(m[i], mt);
      const float f = __expf(m[i] - mnew);
      float ps = 0.0f;
#pragma unroll
      for (int j = 0; j < 4; ++j) {
        p[i][j] = __expf(p[i][j] - mnew);
        ps += p[i][j];
      }
      ps += __shfl_xor(ps, 1);
      ps += __shfl_xor(ps, 2);
      ps += __shfl_xor(ps, 4);
      ps += __shfl_xor(ps, 8);
      l[i] = l[i] * f + ps;
      m[i] = mnew;
#pragma unroll
      for (int j = 0; j < 4; ++j) acc[i][j] *= f;
    }

    // O += P @ V  (fetch P[i][j] from its owner lane via shuffle)
    const int lbase = lane & 48;
#pragma unroll
    for (int j = 0; j < 64; ++j) {
      const float4 v4 = *(const float4*)&Vs[j][tx * 4];
      const int src = lbase | (j >> 2);
#pragma unroll
      for (int i = 0; i < 4; ++i) {
        const float pij = __shfl(p[i][j & 3], src);
        acc[i][0] = fmaf(pij, v4.x, acc[i][0]);
        acc[i][1] = fmaf(pij, v4.y, acc[i][1]);
        acc[i][2] = fmaf(pij, v4.z, acc[i][2]);
        acc[i][3] = fmaf(pij, v4.w, acc[i][3]);
      }
    }
    __syncthreads();
  }

#pragma unroll
  for (int i = 0; i < 4; ++i) {
    const float inv = 1.0f / l[i];
    float4 r4;
    r4.x = acc[i][0] * inv;
    r4.y = acc[i][1] * inv;
    r4.z = acc[i][2] * inv;
    r4.w = acc[i][3] * inv;
    *(float4*)(op + base + (long)(q0 + ty * 4 + i) * HID + (tx * 4)) = r4;
  }
}

// ---------------------------------------------------------------------------
// [B][S][C] -> [B][C][S] transpose
// ---------------------------------------------------------------------------
__global__ void transpose_f32(const float* __restrict__ in,
                              float* __restrict__ out) {
  __shared__ float tile[32][33];
  const int b = blockIdx.z;
  const int s0 = blockIdx.x * 32;
  const int c0 = blockIdx.y * 32;
  const float* ib = in + (long)b * SEQ * CDIM;
  float* ob = out + (long)b * SEQ * CDIM;
  const int txx = threadIdx.x, tyy = threadIdx.y;
  for (int i = tyy; i < 32; i += 8)
    tile[i][txx] = ib[(long)(s0 + i) * CDIM + (c0 + txx)];
  __syncthreads();
  for (int i = tyy; i < 32; i += 8)
    ob[(long)(c0 + i) * SEQ + (s0 + txx)] = tile[txx][i];
}

// ---------------------------------------------------------------------------
extern "C" void kernel_launch(void* const* d_in, const int* in_sizes, int n_in,
                              void* d_out, int out_size, void* d_ws,
                              size_t ws_size, hipStream_t stream) {
  const float* x   = (const float*)d_in[0];
  const float* ctx = (const float*)d_in[1];
  const float* Wi  = (const float*)d_in[2];
  const float* bi  = (const float*)d_in[3];
  const float* Wc  = (const float*)d_in[4];
  const float* bc  = (const float*)d_in[5];
  const float* Wq  = (const float*)d_in[6];
  const float* Wk  = (const float*)d_in[7];
  const float* Wv  = (const float*)d_in[8];
  const float* Wo1 = (const float*)d_in[9];
  const float* bo1 = (const float*)d_in[10];
  const float* Wo2 = (const float*)d_in[11];
  const float* bo2 = (const float*)d_in[12];
  float* out = (float*)d_out;

  const size_t BUF = (size_t)NB * SEQ * HID;  // 4M floats = 16.78 MB
  float* b0 = (float*)d_ws;   // x_proj -> k -> t1
  float* b1 = b0 + BUF;       // ctx_proj -> attn_out
  float* b2 = b1 + BUF;       // q -> y
  float* b3 = b2 + BUF;       // v

  const dim3 ggrid(HID / 64, SEQ / 64, NB);
  const dim3 gblock(256);
  const long AS_IN = (long)CDIM * SEQ;   // batch stride of x/context [C][S]
  const long AS_SQ = (long)SEQ * HID;    // batch stride of [S][HID] tensors

  // x_proj = x^T @ Wi + bi -> b0
  gemm_f32<true, false, true><<<ggrid, gblock, 0, stream>>>(
      x, Wi, bi, b0, SEQ, HID, CDIM, AS_IN, AS_SQ);
  // ctx_proj = ctx^T @ Wc + bc -> b1
  gemm_f32<true, false, true><<<ggrid, gblock, 0, stream>>>(
      ctx, Wc, bc, b1, SEQ, HID, CDIM, AS_IN, AS_SQ);
  // q = x_proj @ Wq -> b2
  gemm_f32<false, false, false><<<ggrid, gblock, 0, stream>>>(
      b0, Wq, nullptr, b2, SEQ, HID, HID, AS_SQ, AS_SQ);
  // k = ctx_proj @ Wk -> b0 (x_proj dead)
  gemm_f32<false, false, false><<<ggrid, gblock, 0, stream>>>(
      b1, Wk, nullptr, b0, SEQ, HID, HID, AS_SQ, AS_SQ);
  // v = ctx_proj @ Wv -> b3
  gemm_f32<false, false, false><<<ggrid, gblock, 0, stream>>>(
      b1, Wv, nullptr, b3, SEQ, HID, HID, AS_SQ, AS_SQ);
  // attention(q=b2, k=b0, v=b3) -> b1 (ctx_proj dead)
  attn_f32<<<dim3(SEQ / 64, NHEADS, NB), gblock, 0, stream>>>(b2, b0, b3, b1);
  // t1 = gelu(attn_out @ Wo1 + bo1) -> b0 (k dead)
  gemm_f32<false, true, true><<<ggrid, gblock, 0, stream>>>(
      b1, Wo1, bo1, b0, SEQ, HID, HID, AS_SQ, AS_SQ);
  // y = t1 @ Wo2 + bo2 -> b2 (q dead)
  gemm_f32<false, false, true><<<ggrid, gblock, 0, stream>>>(
      b0, Wo2, bo2, b2, SEQ, CDIM, HID, AS_SQ, AS_SQ);
  // out[b][c][s] = y[b][s][c]
  transpose_f32<<<dim3(SEQ / 32, CDIM / 32, NB), dim3(32, 8), 0, stream>>>(
      b2, out);
}

// Round 2
// 658.309 us; speedup vs baseline: 2.7465x; 2.7465x over previous
//
#include <hip/hip_runtime.h>

#define NB 2
#define CDIM 512
#define SEQ 4096
#define HID 512
#define NHEADS 8
#define HDIM 64
#define ATT_SCALE 0.125f

typedef float f32x4 __attribute__((ext_vector_type(4)));
typedef short bf16x8 __attribute__((ext_vector_type(8)));
typedef short s16x4 __attribute__((ext_vector_type(4)));

static __device__ __forceinline__ short f2bf(float f) {
  unsigned u = __float_as_uint(f);
  u = (u + 0x7fffu + ((u >> 16) & 1u)) >> 16;
  return (short)u;
}

// ---------------------------------------------------------------------------
// Tiled fp32 GEMM (unchanged from R0): out = A @ W (+bias) (+gelu)
// ---------------------------------------------------------------------------
template <bool ATRANS, bool DO_GELU, bool HAS_BIAS>
__global__ __launch_bounds__(256) void gemm_f32(
    const float* __restrict__ A, const float* __restrict__ W,
    const float* __restrict__ bias, float* __restrict__ out,
    const int M, const int N, const int K,
    const long aStride, const long oStride) {
  __shared__ __align__(16) float As[16][68];
  __shared__ __align__(16) float Bs[16][68];
  const int t = threadIdx.x;
  const int tx = t & 15, ty = t >> 4;
  const int m0 = blockIdx.y * 64, n0 = blockIdx.x * 64;
  const float* Ab = A + (long)blockIdx.z * aStride;
  float* Ob = out + (long)blockIdx.z * oStride;
  float acc[4][4] = {};

  for (int k0 = 0; k0 < K; k0 += 16) {
    if (ATRANS) {
      const int r = t >> 4, c = (t & 15) * 4;
      const float4 a4 = *(const float4*)(Ab + (long)(k0 + r) * M + (m0 + c));
      *(float4*)&As[r][c] = a4;
    } else {
      const int r = t >> 2, c = (t & 3) * 4;
      const float4 a4 = *(const float4*)(Ab + (long)(m0 + r) * K + (k0 + c));
      As[c + 0][r] = a4.x;
      As[c + 1][r] = a4.y;
      As[c + 2][r] = a4.z;
      As[c + 3][r] = a4.w;
    }
    {
      const int r = t >> 4, c = (t & 15) * 4;
      const float4 b4 = *(const float4*)(W + (long)(k0 + r) * N + (n0 + c));
      *(float4*)&Bs[r][c] = b4;
    }
    __syncthreads();
#pragma unroll
    for (int k = 0; k < 16; ++k) {
      const float4 a4 = *(const float4*)&As[k][ty * 4];
      const float4 b4 = *(const float4*)&Bs[k][tx * 4];
      const float av[4] = {a4.x, a4.y, a4.z, a4.w};
      const float bv[4] = {b4.x, b4.y, b4.z, b4.w};
#pragma unroll
      for (int i = 0; i < 4; ++i)
#pragma unroll
        for (int j = 0; j < 4; ++j)
          acc[i][j] = fmaf(av[i], bv[j], acc[i][j]);
    }
    __syncthreads();
  }

#pragma unroll
  for (int i = 0; i < 4; ++i) {
    const int m = m0 + ty * 4 + i;
    float vv[4];
#pragma unroll
    for (int j = 0; j < 4; ++j) {
      float v = acc[i][j];
      if (HAS_BIAS) v += bias[n0 + tx * 4 + j];
      if (DO_GELU) v = 0.5f * v * (1.0f + erff(v * 0.7071067811865476f));
      vv[j] = v;
    }
    float4 r4;
    r4.x = vv[0]; r4.y = vv[1]; r4.z = vv[2]; r4.w = vv[3];
    *(float4*)(Ob + (long)m * N + (n0 + tx * 4)) = r4;
  }
}

// ---------------------------------------------------------------------------
// Flash attention with bf16 MFMA (16x16x32), fp32 online softmax.
// Block = 256 threads = 4 waves; each wave owns 16 q rows. KV tile = 64.
// S^T = mfma(A=K, B=Q): lane holds P^T column q=lane&15, keys 4g+r per tile.
// PV:  O^T = mfma(A=V^T frags, B=P^T from D regs) -- zero P shuffles.
// K LDS row-major [key][d], V LDS transposed [d][key]; both XOR-swizzled.
// ---------------------------------------------------------------------------
__global__ __launch_bounds__(256) void attn_mfma(
    const float* __restrict__ qp, const float* __restrict__ kp,
    const float* __restrict__ vp, float* __restrict__ op) {
  __shared__ __align__(16) char smem[16384];
  char* Kl = smem;          // [64 key][64 d] bf16, byte = key*128 + d*2, ^((key&7)<<4)
  char* Vt = smem + 8192;   // [64 d][64 key] bf16, byte = d*128 + key*2, ^((d&7)<<4)
  const int t = threadIdx.x;
  const int lane = t & 63;
  const int wave = t >> 6;
  const int l15 = lane & 15;
  const int g = lane >> 4;
  const long base = (long)blockIdx.z * SEQ * HID + (long)blockIdx.y * HDIM;
  const int q0 = blockIdx.x * 64;

  // staging thread mapping
  const int sr = t >> 2;        // row (K: key, V: d), 0..63
  const int sc = t & 3;         // 16-col chunk
  const int swzS = (sr & 7) << 4;
  const int sb = sr * 128 + sc * 32;

  // fragment-read swizzle (row = l15 within each 16-row tile; 16 % 8 == 0)
  const int swzl = (l15 & 7) << 4;
  const int kfb = l15 * 128 + g * 16;  // K frag base (col byte = g*16 + kk*64)
  const int vfb = l15 * 128 + g * 8;   // V frag base (col byte = kc*64 + h*32 + g*8)

  // --- Q fragments in registers, scale folded in (0.125 exact in bf16) ---
  bf16x8 qf[2];
  {
    const float* qrow = qp + base + (long)(q0 + wave * 16 + l15) * HID + g * 8;
    const float4 a0 = *(const float4*)(qrow);
    const float4 a1 = *(const float4*)(qrow + 4);
    const float4 a2 = *(const float4*)(qrow + 32);
    const float4 a3 = *(const float4*)(qrow + 36);
    const float t0[8] = {a0.x, a0.y, a0.z, a0.w, a1.x, a1.y, a1.z, a1.w};
    const float t1[8] = {a2.x, a2.y, a2.z, a2.w, a3.x, a3.y, a3.z, a3.w};
#pragma unroll
    for (int e = 0; e < 8; ++e) {
      qf[0][e] = f2bf(t0[e] * ATT_SCALE);
      qf[1][e] = f2bf(t1[e] * ATT_SCALE);
    }
  }

  float mrun = -1e30f, lrun = 0.0f;
  f32x4 acc[4];
#pragma unroll
  for (int dt = 0; dt < 4; ++dt) acc[dt] = (f32x4){0.f, 0.f, 0.f, 0.f};

  for (int j0 = 0; j0 < SEQ; j0 += 64) {
    __syncthreads();
    // ---- stage K tile (row-major) ----
    {
      const float* kr = kp + base + (long)(j0 + sr) * HID + sc * 16;
      const float4 c0 = *(const float4*)(kr);
      const float4 c1 = *(const float4*)(kr + 4);
      const float4 c2 = *(const float4*)(kr + 8);
      const float4 c3 = *(const float4*)(kr + 12);
      const float tf[16] = {c0.x, c0.y, c0.z, c0.w, c1.x, c1.y, c1.z, c1.w,
                            c2.x, c2.y, c2.z, c2.w, c3.x, c3.y, c3.z, c3.w};
      union { short s[16]; int4 q[2]; } uk;
#pragma unroll
      for (int m = 0; m < 16; ++m) uk.s[m] = f2bf(tf[m]);
      *(int4*)(Kl + (sb ^ swzS)) = uk.q[0];
      *(int4*)(Kl + ((sb + 16) ^ swzS)) = uk.q[1];
    }
    // ---- stage V tile transposed ----
    {
      const float* vr = vp + base + (long)(j0 + sc * 16) * HID + sr;
      union { short s[16]; int4 q[2]; } uv;
#pragma unroll
      for (int j = 0; j < 16; ++j) uv.s[j] = f2bf(vr[(long)j * HID]);
      *(int4*)(Vt + (sb ^ swzS)) = uv.q[0];
      *(int4*)(Vt + ((sb + 16) ^ swzS)) = uv.q[1];
    }
    __syncthreads();

    // ---- S^T = K @ Q^T (per key-tile of 16) ----
    f32x4 st[4];
#pragma unroll
    for (int kt = 0; kt < 4; ++kt) {
      const bf16x8 ka0 = *(const bf16x8*)(Kl + ((kt * 2048 + kfb) ^ swzl));
      const bf16x8 ka1 = *(const bf16x8*)(Kl + ((kt * 2048 + kfb + 64) ^ swzl));
      f32x4 s = {0.f, 0.f, 0.f, 0.f};
      s = __builtin_amdgcn_mfma_f32_16x16x32_bf16(ka0, qf[0], s, 0, 0, 0);
      s = __builtin_amdgcn_mfma_f32_16x16x32_bf16(ka1, qf[1], s, 0, 0, 0);
      st[kt] = s;
    }

    // ---- online softmax (lane owns one q column; keys 4g+r per tile) ----
    float mt = -1e30f;
#pragma unroll
    for (int kt = 0; kt < 4; ++kt)
#pragma unroll
      for (int r = 0; r < 4; ++r) mt = fmaxf(mt, st[kt][r]);
    mt = fmaxf(mt, __shfl_xor(mt, 16));
    mt = fmaxf(mt, __shfl_xor(mt, 32));
    const float mnew = fmaxf(mrun, mt);
    const float corr = __expf(mrun - mnew);
    float ps = 0.0f;
#pragma unroll
    for (int kt = 0; kt < 4; ++kt)
#pragma unroll
      for (int r = 0; r < 4; ++r) {
        const float p = __expf(st[kt][r] - mnew);
        st[kt][r] = p;
        ps += p;
      }
    ps += __shfl_xor(ps, 16);
    ps += __shfl_xor(ps, 32);
    lrun = lrun * corr + ps;
    mrun = mnew;
#pragma unroll
    for (int dt = 0; dt < 4; ++dt)
#pragma unroll
      for (int r = 0; r < 4; ++r) acc[dt][r] *= corr;

    // ---- pack P^T into bf16 B-frags: e = h*4 + r <-> key = 32kc+16h+4g+r ----
    bf16x8 pb[2];
#pragma unroll
    for (int kc = 0; kc < 2; ++kc)
#pragma unroll
      for (int h = 0; h < 2; ++h)
#pragma unroll
        for (int r = 0; r < 4; ++r) pb[kc][h * 4 + r] = f2bf(st[kc * 2 + h][r]);

    // ---- O^T += V^T @ P^T ----
#pragma unroll
    for (int dt = 0; dt < 4; ++dt) {
      union { bf16x8 v8; s16x4 v4[2]; } va0, va1;
      va0.v4[0] = *(const s16x4*)(Vt + ((dt * 2048 + vfb) ^ swzl));
      va0.v4[1] = *(const s16x4*)(Vt + ((dt * 2048 + vfb + 32) ^ swzl));
      va1.v4[0] = *(const s16x4*)(Vt + ((dt * 2048 + vfb + 64) ^ swzl));
      va1.v4[1] = *(const s16x4*)(Vt + ((dt * 2048 + vfb + 96) ^ swzl));
      acc[dt] = __builtin_amdgcn_mfma_f32_16x16x32_bf16(va0.v8, pb[0], acc[dt], 0, 0, 0);
      acc[dt] = __builtin_amdgcn_mfma_f32_16x16x32_bf16(va1.v8, pb[1], acc[dt], 0, 0, 0);
    }
  }

  // ---- epilogue: O[q][d] = acc / l ----
  const float inv = 1.0f / lrun;
  float* orow = op + base + (long)(q0 + wave * 16 + l15) * HID;
#pragma unroll
  for (int dt = 0; dt < 4; ++dt)
#pragma unroll
    for (int r = 0; r < 4; ++r)
      orow[dt * 16 + g * 4 + r] = acc[dt][r] * inv;
}

// ---------------------------------------------------------------------------
// [B][S][C] -> [B][C][S] transpose
// ---------------------------------------------------------------------------
__global__ void transpose_f32(const float* __restrict__ in,
                              float* __restrict__ out) {
  __shared__ float tile[32][33];
  const int b = blockIdx.z;
  const int s0 = blockIdx.x * 32;
  const int c0 = blockIdx.y * 32;
  const float* ib = in + (long)b * SEQ * CDIM;
  float* ob = out + (long)b * SEQ * CDIM;
  const int txx = threadIdx.x, tyy = threadIdx.y;
  for (int i = tyy; i < 32; i += 8)
    tile[i][txx] = ib[(long)(s0 + i) * CDIM + (c0 + txx)];
  __syncthreads();
  for (int i = tyy; i < 32; i += 8)
    ob[(long)(c0 + i) * SEQ + (s0 + txx)] = tile[txx][i];
}

// ---------------------------------------------------------------------------
extern "C" void kernel_launch(void* const* d_in, const int* in_sizes, int n_in,
                              void* d_out, int out_size, void* d_ws,
                              size_t ws_size, hipStream_t stream) {
  const float* x   = (const float*)d_in[0];
  const float* ctx = (const float*)d_in[1];
  const float* Wi  = (const float*)d_in[2];
  const float* bi  = (const float*)d_in[3];
  const float* Wc  = (const float*)d_in[4];
  const float* bc  = (const float*)d_in[5];
  const float* Wq  = (const float*)d_in[6];
  const float* Wk  = (const float*)d_in[7];
  const float* Wv  = (const float*)d_in[8];
  const float* Wo1 = (const float*)d_in[9];
  const float* bo1 = (const float*)d_in[10];
  const float* Wo2 = (const float*)d_in[11];
  const float* bo2 = (const float*)d_in[12];
  float* out = (float*)d_out;

  const size_t BUF = (size_t)NB * SEQ * HID;
  float* b0 = (float*)d_ws;
  float* b1 = b0 + BUF;
  float* b2 = b1 + BUF;
  float* b3 = b2 + BUF;

  const dim3 ggrid(HID / 64, SEQ / 64, NB);
  const dim3 gblock(256);
  const long AS_IN = (long)CDIM * SEQ;
  const long AS_SQ = (long)SEQ * HID;

  gemm_f32<true, false, true><<<ggrid, gblock, 0, stream>>>(
      x, Wi, bi, b0, SEQ, HID, CDIM, AS_IN, AS_SQ);
  gemm_f32<true, false, true><<<ggrid, gblock, 0, stream>>>(
      ctx, Wc, bc, b1, SEQ, HID, CDIM, AS_IN, AS_SQ);
  gemm_f32<false, false, false><<<ggrid, gblock, 0, stream>>>(
      b0, Wq, nullptr, b2, SEQ, HID, HID, AS_SQ, AS_SQ);
  gemm_f32<false, false, false><<<ggrid, gblock, 0, stream>>>(
      b1, Wk, nullptr, b0, SEQ, HID, HID, AS_SQ, AS_SQ);
  gemm_f32<false, false, false><<<ggrid, gblock, 0, stream>>>(
      b1, Wv, nullptr, b3, SEQ, HID, HID, AS_SQ, AS_SQ);
  attn_mfma<<<dim3(SEQ / 64, NHEADS, NB), gblock, 0, stream>>>(b2, b0, b3, b1);
  gemm_f32<false, true, true><<<ggrid, gblock, 0, stream>>>(
      b1, Wo1, bo1, b0, SEQ, HID, HID, AS_SQ, AS_SQ);
  gemm_f32<false, false, true><<<ggrid, gblock, 0, stream>>>(
      b0, Wo2, bo2, b2, SEQ, CDIM, HID, AS_SQ, AS_SQ);
  transpose_f32<<<dim3(SEQ / 32, CDIM / 32, NB), dim3(32, 8), 0, stream>>>(
      b2, out);
}

// Round 3
// 349.592 us; speedup vs baseline: 5.1718x; 1.8831x over previous
//
#include <hip/hip_runtime.h>

#define SEQ 4096
#define CDIM 512
#define HID 512
#define NB 2
#define NHEADS 8
#define HDIM 64

typedef float f32x4 __attribute__((ext_vector_type(4)));
typedef short bf16x8 __attribute__((ext_vector_type(8)));

static __device__ __forceinline__ short f2bf(float f) {
  unsigned u = __float_as_uint(f);
  u = (u + 0x7fffu + ((u >> 16) & 1u)) >> 16;
  return (short)u;
}
static __device__ __forceinline__ float bf2f(short h) {
  return __uint_as_float(((unsigned)(unsigned short)h) << 16);
}

// ---------------------------------------------------------------------------
// prep_w: W[k][n] fp32 -> Wt_hi[n][k], Wt_lo[n][k] bf16 (Wq scaled by 0.125)
// ---------------------------------------------------------------------------
__global__ __launch_bounds__(256) void prep_w(
    const float* Wi, const float* Wc, const float* Wq, const float* Wk,
    const float* Wv, const float* Wo1, const float* Wo2,
    unsigned short* wth, unsigned short* wtl) {
  __shared__ float tile[32][33];
  const int z = blockIdx.z;
  const float* src;
  float scale = 1.0f;
  switch (z) {
    case 0: src = Wi; break;
    case 1: src = Wc; break;
    case 2: src = Wq; scale = 0.125f; break;
    case 3: src = Wk; break;
    case 4: src = Wv; break;
    case 5: src = Wo1; break;
    default: src = Wo2; break;
  }
  const int n0 = blockIdx.x * 32, k0 = blockIdx.y * 32;
  const int tx = threadIdx.x, ty = threadIdx.y;
  for (int i = ty; i < 32; i += 8)
    tile[i][tx] = src[(k0 + i) * 512 + n0 + tx];
  __syncthreads();
  unsigned short* oh = wth + z * 262144;
  unsigned short* ol = wtl + z * 262144;
  for (int i = ty; i < 32; i += 8) {
    const float v = tile[tx][i] * scale;  // = W[k0+tx][n0+i]*scale
    const short h = f2bf(v);
    oh[(n0 + i) * 512 + k0 + tx] = (unsigned short)h;
    ol[(n0 + i) * 512 + k0 + tx] = (unsigned short)f2bf(v - bf2f(h));
  }
}

// ---------------------------------------------------------------------------
// prep_x: in [b][c][s] fp32 -> hi/lo planes [b][s][c] bf16
// ---------------------------------------------------------------------------
__global__ __launch_bounds__(256) void prep_x(
    const float* __restrict__ in, unsigned short* __restrict__ oh,
    unsigned short* __restrict__ ol) {
  __shared__ float tile[32][33];
  const int b = blockIdx.z;
  const int s0 = blockIdx.x * 32, c0 = blockIdx.y * 32;
  const int tx = threadIdx.x, ty = threadIdx.y;
  const float* ib = in + (long)b * CDIM * SEQ;
  for (int i = ty; i < 32; i += 8)
    tile[i][tx] = ib[(long)(c0 + i) * SEQ + s0 + tx];
  __syncthreads();
  const long ob = (long)b * SEQ * CDIM;
  for (int i = ty; i < 32; i += 8) {
    const float v = tile[tx][i];  // = in[c0+tx][s0+i]
    const short h = f2bf(v);
    oh[ob + (long)(s0 + i) * CDIM + c0 + tx] = (unsigned short)h;
    ol[ob + (long)(s0 + i) * CDIM + c0 + tx] = (unsigned short)f2bf(v - bf2f(h));
  }
}

// ---------------------------------------------------------------------------
// Split-bf16 MFMA GEMM. A planes [b][m][k] (hi,lo), W planes [n][k] (hi,lo).
// Y = A@W ~= Ah Wh + Ah Wl + Al Wh, fp32 accumulate (16x16x32 MFMA).
// Block 256 thr = 4 waves (2x2), tile 128x128, BK=32. LDS rows are 128 B
// ([k-hi 64B | k-lo 64B]), XOR-swizzled (slot ^= row&7) -> conflict-free.
// TSTORE=0: D row=n (A-op=W) -> store plane[m][n], f32x4 spans n (coalesced).
// TSTORE=1: D row=m (A-op=Act) -> store plane[n][m], spans m (transposed store).
// ---------------------------------------------------------------------------
#define OUT_DUAL 0
#define OUT_HI 1
#define OUT_F32 2

template <bool TSTORE, int OMODE, bool DO_GELU, bool HASB>
__global__ __launch_bounds__(256) void gemm_split(
    const unsigned short* __restrict__ Ah, const unsigned short* __restrict__ Al,
    const unsigned short* __restrict__ Wth, const unsigned short* __restrict__ Wtl,
    const float* __restrict__ bias, void* __restrict__ outA,
    void* __restrict__ outB) {
  __shared__ __align__(16) char lds[32768];
  char* LA = lds;          // Act tile [128 m][128 B]
  char* LW = lds + 16384;  // W tile [128 n][128 B]
  const int t = threadIdx.x;
  const int lane = t & 63;
  const int wave = t >> 6;
  const int l15 = lane & 15, g = lane >> 4;
  const int wm = wave >> 1, wn = wave & 1;
  const int m0 = blockIdx.y * 128, n0 = blockIdx.x * 128;
  const int bz = blockIdx.z;
  const long abase = (long)bz * SEQ * 512;

  const int srow = t >> 1, sh = t & 1;
  const unsigned short* arow = Ah + abase + (long)(m0 + srow) * 512 + sh * 16;
  const unsigned short* alrow = Al + abase + (long)(m0 + srow) * 512 + sh * 16;
  const unsigned short* whrow = Wth + (long)(n0 + srow) * 512 + sh * 16;
  const unsigned short* wlrow = Wtl + (long)(n0 + srow) * 512 + sh * 16;
  const int wbyte = srow * 128;
  const int wsw = (srow & 7) << 4;
  const int s_h0 = ((2 * sh) << 4) ^ wsw;
  const int s_h1 = ((2 * sh + 1) << 4) ^ wsw;
  const int s_l0 = ((4 + 2 * sh) << 4) ^ wsw;
  const int s_l1 = ((5 + 2 * sh) << 4) ^ wsw;

  f32x4 acc[4][4];
#pragma unroll
  for (int p = 0; p < 4; ++p)
#pragma unroll
    for (int q = 0; q < 4; ++q) acc[p][q] = (f32x4){0.f, 0.f, 0.f, 0.f};

  for (int k0 = 0; k0 < 512; k0 += 32) {
    const int4 va0 = *(const int4*)(arow + k0);
    const int4 va1 = *(const int4*)(arow + k0 + 8);
    const int4 vl0 = *(const int4*)(alrow + k0);
    const int4 vl1 = *(const int4*)(alrow + k0 + 8);
    const int4 vw0 = *(const int4*)(whrow + k0);
    const int4 vw1 = *(const int4*)(whrow + k0 + 8);
    const int4 vx0 = *(const int4*)(wlrow + k0);
    const int4 vx1 = *(const int4*)(wlrow + k0 + 8);
    __syncthreads();  // previous iteration's frag reads done
    *(int4*)(LA + wbyte + s_h0) = va0;
    *(int4*)(LA + wbyte + s_h1) = va1;
    *(int4*)(LA + wbyte + s_l0) = vl0;
    *(int4*)(LA + wbyte + s_l1) = vl1;
    *(int4*)(LW + wbyte + s_h0) = vw0;
    *(int4*)(LW + wbyte + s_h1) = vw1;
    *(int4*)(LW + wbyte + s_l0) = vx0;
    *(int4*)(LW + wbyte + s_l1) = vx1;
    __syncthreads();

    const char* fAp = TSTORE ? LA : LW;  // A-operand side = D rows
    const char* fBp = TSTORE ? LW : LA;  // B-operand side = D cols
    bf16x8 fbh[4], fbl[4];
#pragma unroll
    for (int q = 0; q < 4; ++q) {
      const int r = wn * 64 + q * 16 + l15;
      const char* rp = fBp + r * 128;
      const int sw = (r & 7) << 4;
      fbh[q] = *(const bf16x8*)(rp + ((g << 4) ^ sw));
      fbl[q] = *(const bf16x8*)(rp + (((4 + g) << 4) ^ sw));
    }
#pragma unroll
    for (int p = 0; p < 4; ++p) {
      const int r = wm * 64 + p * 16 + l15;
      const char* rp = fAp + r * 128;
      const int sw = (r & 7) << 4;
      const bf16x8 fah = *(const bf16x8*)(rp + ((g << 4) ^ sw));
      const bf16x8 fal = *(const bf16x8*)(rp + (((4 + g) << 4) ^ sw));
#pragma unroll
      for (int q = 0; q < 4; ++q) {
        acc[p][q] = __builtin_amdgcn_mfma_f32_16x16x32_bf16(fah, fbh[q], acc[p][q], 0, 0, 0);
        acc[p][q] = __builtin_amdgcn_mfma_f32_16x16x32_bf16(fah, fbl[q], acc[p][q], 0, 0, 0);
        acc[p][q] = __builtin_amdgcn_mfma_f32_16x16x32_bf16(fal, fbh[q], acc[p][q], 0, 0, 0);
      }
    }
  }

  const long obase = (long)bz * 512 * SEQ;
#pragma unroll
  for (int p = 0; p < 4; ++p)
#pragma unroll
    for (int q = 0; q < 4; ++q) {
      f32x4 v = acc[p][q];
      if (TSTORE) {
        const int m = m0 + wm * 64 + p * 16 + 4 * g;  // f32x4 spans m
        const int n = n0 + wn * 64 + q * 16 + l15;
        if (HASB) {
          const float b = bias[n];
          v[0] += b; v[1] += b; v[2] += b; v[3] += b;
        }
        if (OMODE == OUT_F32) {
          float4 f;
          f.x = v[0]; f.y = v[1]; f.z = v[2]; f.w = v[3];
          *(float4*)((float*)outA + obase + (long)n * SEQ + m) = f;
        } else {  // OUT_HI, transposed plane [n][m]
          const short4 h4 = make_short4(f2bf(v[0]), f2bf(v[1]), f2bf(v[2]), f2bf(v[3]));
          *(short4*)((unsigned short*)outA + obase + (long)n * SEQ + m) = h4;
        }
      } else {
        const int n = n0 + wm * 64 + p * 16 + 4 * g;  // f32x4 spans n
        const int m = m0 + wn * 64 + q * 16 + l15;
        if (HASB) v += *(const f32x4*)(bias + n);
        if (DO_GELU) {
#pragma unroll
          for (int r = 0; r < 4; ++r)
            v[r] = 0.5f * v[r] * (1.0f + erff(v[r] * 0.7071067811865476f));
        }
        unsigned short* oA = (unsigned short*)outA + obase + (long)m * 512 + n;
        if (OMODE == OUT_DUAL) {
          short h[4], l[4];
#pragma unroll
          for (int r = 0; r < 4; ++r) {
            h[r] = f2bf(v[r]);
            l[r] = f2bf(v[r] - bf2f(h[r]));
          }
          *(short4*)oA = make_short4(h[0], h[1], h[2], h[3]);
          *(short4*)((unsigned short*)outB + obase + (long)m * 512 + n) =
              make_short4(l[0], l[1], l[2], l[3]);
        } else {  // OUT_HI
          *(short4*)oA = make_short4(f2bf(v[0]), f2bf(v[1]), f2bf(v[2]), f2bf(v[3]));
        }
      }
    }
}

// ---------------------------------------------------------------------------
// Flash attention, bf16 MFMA; inputs are bf16 planes: Q,K [b][s][512] (hi),
// Vt [b][512 d][4096 s] (hi, pre-transposed). Scale pre-folded into Wq.
// Output: hi/lo bf16 planes [b][s][512]. Structure as R2 (verified layouts).
// ---------------------------------------------------------------------------
__global__ __launch_bounds__(256) void attn_mfma(
    const unsigned short* __restrict__ qh, const unsigned short* __restrict__ kh,
    const unsigned short* __restrict__ vt, unsigned short* __restrict__ oh,
    unsigned short* __restrict__ ol) {
  __shared__ __align__(16) char smem[16384];
  char* Kl = smem;         // [64 key][64 d] bf16, swizzled
  char* Vt = smem + 8192;  // [64 d][64 key] bf16, swizzled
  const int t = threadIdx.x;
  const int lane = t & 63;
  const int wave = t >> 6;
  const int l15 = lane & 15;
  const int g = lane >> 4;
  const int hd = blockIdx.y;
  const int bz = blockIdx.z;
  const int q0 = blockIdx.x * 64;
  const long sbase = (long)bz * SEQ * 512;          // [s][512] planes
  const long tbase = (long)bz * 512 * SEQ;          // Vt plane

  const int sr = t >> 2;  // 0..63
  const int sc = t & 3;
  const int swzS = (sr & 7) << 4;
  const int sb = sr * 128 + sc * 32;

  const int swzl = (l15 & 7) << 4;
  const int kfb = l15 * 128 + g * 16;
  const int vfb = l15 * 128 + g * 8;

  // Q fragments straight from bf16 plane (scale already in Wq)
  bf16x8 qf[2];
  {
    const unsigned short* qrow = qh + sbase + (long)(q0 + wave * 16 + l15) * 512 + hd * 64 + g * 8;
    qf[0] = *(const bf16x8*)(qrow);
    qf[1] = *(const bf16x8*)(qrow + 32);
  }

  float mrun = -1e30f, lrun = 0.0f;
  f32x4 acc[4];
#pragma unroll
  for (int dt = 0; dt < 4; ++dt) acc[dt] = (f32x4){0.f, 0.f, 0.f, 0.f};

  for (int j0 = 0; j0 < SEQ; j0 += 64) {
    __syncthreads();
    {  // stage K tile: rows of Kh (pure copy)
      const unsigned short* kr = kh + sbase + (long)(j0 + sr) * 512 + hd * 64 + sc * 16;
      const int4 c0 = *(const int4*)(kr);
      const int4 c1 = *(const int4*)(kr + 8);
      *(int4*)(Kl + (sb ^ swzS)) = c0;
      *(int4*)(Kl + ((sb + 16) ^ swzS)) = c1;
    }
    {  // stage V^T tile: rows of Vt plane (pure copy)
      const unsigned short* vr = vt + tbase + (long)(hd * 64 + sr) * SEQ + j0 + sc * 16;
      const int4 c0 = *(const int4*)(vr);
      const int4 c1 = *(const int4*)(vr + 8);
      *(int4*)(Vt + (sb ^ swzS)) = c0;
      *(int4*)(Vt + ((sb + 16) ^ swzS)) = c1;
    }
    __syncthreads();

    // S^T = K @ Q^T
    f32x4 st[4];
#pragma unroll
    for (int kt = 0; kt < 4; ++kt) {
      const bf16x8 ka0 = *(const bf16x8*)(Kl + ((kt * 2048 + kfb) ^ swzl));
      const bf16x8 ka1 = *(const bf16x8*)(Kl + ((kt * 2048 + kfb + 64) ^ swzl));
      f32x4 s = {0.f, 0.f, 0.f, 0.f};
      s = __builtin_amdgcn_mfma_f32_16x16x32_bf16(ka0, qf[0], s, 0, 0, 0);
      s = __builtin_amdgcn_mfma_f32_16x16x32_bf16(ka1, qf[1], s, 0, 0, 0);
      st[kt] = s;
    }

    // online softmax (lane owns q column l15; keys 4g+r per 16-tile)
    float mt = -1e30f;
#pragma unroll
    for (int kt = 0; kt < 4; ++kt)
#pragma unroll
      for (int r = 0; r < 4; ++r) mt = fmaxf(mt, st[kt][r]);
    mt = fmaxf(mt, __shfl_xor(mt, 16));
    mt = fmaxf(mt, __shfl_xor(mt, 32));
    const float mnew = fmaxf(mrun, mt);
    const float corr = __expf(mrun - mnew);
    float ps = 0.0f;
#pragma unroll
    for (int kt = 0; kt < 4; ++kt)
#pragma unroll
      for (int r = 0; r < 4; ++r) {
        const float p = __expf(st[kt][r] - mnew);
        st[kt][r] = p;
        ps += p;
      }
    ps += __shfl_xor(ps, 16);
    ps += __shfl_xor(ps, 32);
    lrun = lrun * corr + ps;
    mrun = mnew;
#pragma unroll
    for (int dt = 0; dt < 4; ++dt)
#pragma unroll
      for (int r = 0; r < 4; ++r) acc[dt][r] *= corr;

    // pack P^T -> bf16 B-frags
    bf16x8 pb[2];
#pragma unroll
    for (int kc = 0; kc < 2; ++kc)
#pragma unroll
      for (int h = 0; h < 2; ++h)
#pragma unroll
        for (int r = 0; r < 4; ++r) pb[kc][h * 4 + r] = f2bf(st[kc * 2 + h][r]);

    // O^T += V^T @ P^T
#pragma unroll
    for (int dt = 0; dt < 4; ++dt) {
      union { bf16x8 v8; int2 h[2]; } va0, va1;
      va0.h[0] = *(const int2*)(Vt + ((dt * 2048 + vfb) ^ swzl));
      va0.h[1] = *(const int2*)(Vt + ((dt * 2048 + vfb + 32) ^ swzl));
      va1.h[0] = *(const int2*)(Vt + ((dt * 2048 + vfb + 64) ^ swzl));
      va1.h[1] = *(const int2*)(Vt + ((dt * 2048 + vfb + 96) ^ swzl));
      acc[dt] = __builtin_amdgcn_mfma_f32_16x16x32_bf16(va0.v8, pb[0], acc[dt], 0, 0, 0);
      acc[dt] = __builtin_amdgcn_mfma_f32_16x16x32_bf16(va1.v8, pb[1], acc[dt], 0, 0, 0);
    }
  }

  // epilogue: hi/lo planes
  const float inv = 1.0f / lrun;
  const long orow = sbase + (long)(q0 + wave * 16 + l15) * 512 + hd * 64;
#pragma unroll
  for (int dt = 0; dt < 4; ++dt) {
    short h[4], l[4];
#pragma unroll
    for (int r = 0; r < 4; ++r) {
      const float v = acc[dt][r] * inv;
      h[r] = f2bf(v);
      l[r] = f2bf(v - bf2f(h[r]));
    }
    *(short4*)(oh + orow + dt * 16 + g * 4) = make_short4(h[0], h[1], h[2], h[3]);
    *(short4*)(ol + orow + dt * 16 + g * 4) = make_short4(l[0], l[1], l[2], l[3]);
  }
}

// ---------------------------------------------------------------------------
extern "C" void kernel_launch(void* const* d_in, const int* in_sizes, int n_in,
                              void* d_out, int out_size, void* d_ws,
                              size_t ws_size, hipStream_t stream) {
  const float* x   = (const float*)d_in[0];
  const float* ctx = (const float*)d_in[1];
  const float* Wi  = (const float*)d_in[2];
  const float* bi  = (const float*)d_in[3];
  const float* Wc  = (const float*)d_in[4];
  const float* bc  = (const float*)d_in[5];
  const float* Wq  = (const float*)d_in[6];
  const float* Wk  = (const float*)d_in[7];
  const float* Wv  = (const float*)d_in[8];
  const float* Wo1 = (const float*)d_in[9];
  const float* bo1 = (const float*)d_in[10];
  const float* Wo2 = (const float*)d_in[11];
  const float* bo2 = (const float*)d_in[12];
  float* out = (float*)d_out;

  char* p = (char*)d_ws;
  unsigned short* wth = (unsigned short*)p; p += (size_t)7 * 262144 * 2;
  unsigned short* wtl = (unsigned short*)p; p += (size_t)7 * 262144 * 2;
  const size_t PL = (size_t)NB * SEQ * 512 * 2;  // 8.39 MB per plane
  unsigned short* P1 = (unsigned short*)p; p += PL;
  unsigned short* P2 = (unsigned short*)p; p += PL;
  unsigned short* P3 = (unsigned short*)p; p += PL;
  unsigned short* P4 = (unsigned short*)p; p += PL;
  unsigned short* P5 = (unsigned short*)p; p += PL;
  unsigned short* P6 = (unsigned short*)p; p += PL;

  const dim3 gg(4, 32, NB), gb(256);
  const dim3 pg(16, 16, 7), pb(32, 8);
  const dim3 xg(128, 16, NB);

  prep_w<<<pg, pb, 0, stream>>>(Wi, Wc, Wq, Wk, Wv, Wo1, Wo2, wth, wtl);
  // x -> P1,P2 ; x_proj -> P3,P4
  prep_x<<<xg, pb, 0, stream>>>(x, P1, P2);
  gemm_split<false, OUT_DUAL, false, true><<<gg, gb, 0, stream>>>(
      P1, P2, wth + 0 * 262144, wtl + 0 * 262144, bi, P3, P4);
  // ctx -> P1,P2 ; ctx_proj -> P5,P6
  prep_x<<<xg, pb, 0, stream>>>(ctx, P1, P2);
  gemm_split<false, OUT_DUAL, false, true><<<gg, gb, 0, stream>>>(
      P1, P2, wth + 1 * 262144, wtl + 1 * 262144, bc, P5, P6);
  // Q = x_proj @ (Wq*scale) -> P1 (hi only)
  gemm_split<false, OUT_HI, false, false><<<gg, gb, 0, stream>>>(
      P3, P4, wth + 2 * 262144, wtl + 2 * 262144, nullptr, P1, nullptr);
  // K = ctx_proj @ Wk -> P2 (hi only)
  gemm_split<false, OUT_HI, false, false><<<gg, gb, 0, stream>>>(
      P5, P6, wth + 3 * 262144, wtl + 3 * 262144, nullptr, P2, nullptr);
  // V^T = (ctx_proj @ Wv)^T -> P3 (hi only, [d][s] layout)
  gemm_split<true, OUT_HI, false, false><<<gg, gb, 0, stream>>>(
      P5, P6, wth + 4 * 262144, wtl + 4 * 262144, nullptr, P3, nullptr);
  // attention(Q=P1, K=P2, Vt=P3) -> P4 (hi), P5 (lo)
  attn_mfma<<<dim3(SEQ / 64, NHEADS, NB), gb, 0, stream>>>(P1, P2, P3, P4, P5);
  // t1 = gelu(attn @ Wo1 + bo1) -> P6 (hi), P1 (lo)
  gemm_split<false, OUT_DUAL, true, true><<<gg, gb, 0, stream>>>(
      P4, P5, wth + 5 * 262144, wtl + 5 * 262144, bo1, P6, P1);
  // out[b][c][s] = (t1 @ Wo2 + bo2)^T  (fp32, fused transpose store)
  gemm_split<true, OUT_F32, false, true><<<gg, gb, 0, stream>>>(
      P6, P1, wth + 6 * 262144, wtl + 6 * 262144, bo2, out, nullptr);
}